// Round 5
// baseline (352.471 us; speedup 1.0000x reference)
//
#include <hip/hip_runtime.h>

#define TAGS 64
#define SOS_IDX 1
#define EOS_IDX 2

typedef __attribute__((ext_vector_type(2))) float f2;

// quad_perm DPP: x1 = swap bit0 [1,0,3,2]; x2 = swap bit1 [2,3,0,1]
#define DPP_X1 0xB1
#define DPP_X2 0x4E
#define DPPF(v, ctrl) \
    __int_as_float(__builtin_amdgcn_mov_dpp(__float_as_int(v), (ctrl), 0xF, 0xF, true))

__device__ __forceinline__ float rl(float v, int l) {
    return __int_as_float(__builtin_amdgcn_readlane(__float_as_int(v), l));
}

// One wave per batch; lane i = 4g+c owns tag i.
// x = unnormalized exp-domain score; invariant: score = log(x) + ln2*Ls.
// Step: x' = (E x) * s,  s = exp(h_t[i]) * rcp(z),  z = x_prev[3] (one-step-lagged
// normalization -> z/rcp/log2/s all compute off the critical chain, inside the
// LDS stall). Chain: ds_write x -> 4x ds_read_b128 -> fma tree -> DPP -> 1 mul.
__global__ __launch_bounds__(64, 1) void crf_fwd_kernel(
    const float* __restrict__ h,
    const float* __restrict__ mask,
    const float* __restrict__ trans,
    float* __restrict__ out,
    int S)
{
    const int b = blockIdx.x;
    const int lane = threadIdx.x;
    const int g = lane >> 2;
    const int c = lane & 3;

    __shared__ __align__(16) float u_sh[TAGS];

    // E fragment: slot k holds exp(trans[4g + (c^k)][16c .. 16c+16)) as 8 f2.
    f2 ew2[4][8];
    #pragma unroll
    for (int k = 0; k < 4; ++k) {
        const int row = 4 * g + (c ^ k);
        const float4* tr = reinterpret_cast<const float4*>(trans + row * TAGS + 16 * c);
        #pragma unroll
        for (int q = 0; q < 4; ++q) {
            float4 v = tr[q];
            f2 lo, hi;
            lo.x = __expf(v.x); lo.y = __expf(v.y);   // exp(-10000) -> 0 exact
            hi.x = __expf(v.z); hi.y = __expf(v.w);
            ew2[k][2*q]   = lo;
            ew2[k][2*q+1] = hi;
        }
    }

    const float* hb = h + (size_t)b * (size_t)S * TAGS + lane;
    const float* mb = mask + (size_t)b * (size_t)S;

    float x  = (lane == SOS_IDX) ? 1.0f : 0.0f;  // exp(score0)
    float Ls = 0.0f;                              // sum of log2 of dropped scales

    // h prefetch, depth 8 (coalesced 256B/wave/step)
    float hbuf[8];
    #pragma unroll
    for (int q = 0; q < 8; ++q) {
        int t = (q < S) ? q : (S - 1);
        hbuf[q] = hb[(size_t)t * TAGS];
    }

    // mask: one coalesced load per 64-step chunk, readlane per step. S%64==0.
    const int NC = S >> 6;
    float mreg = mb[lane];

    const float4* u4 = reinterpret_cast<const float4*>(u_sh);

    for (int ch = 0; ch < NC; ++ch) {
        const int cn = (ch + 1 < NC) ? (ch + 1) : ch;
        float mreg_next = mb[(size_t)cn * 64 + lane];   // used 64 steps from now

        for (int t0 = 0; t0 < 64; t0 += 8) {
            float ehq[8];
            #pragma unroll
            for (int q = 0; q < 8; ++q) ehq[q] = __expf(hbuf[q]);
            const int base = ch * 64 + t0 + 8;
            #pragma unroll
            for (int q = 0; q < 8; ++q) {
                int tn = base + q;
                if (tn > S - 1) tn = S - 1;
                hbuf[q] = hb[(size_t)tn * TAGS];
            }

            #pragma unroll
            for (int q = 0; q < 8; ++q) {
                // --- chain head: publish x, start the broadcast reads ---
                u_sh[lane] = x;
                float4 cc0 = u4[(c << 2) + 0];
                float4 cc1 = u4[(c << 2) + 1];
                float4 cc2 = u4[(c << 2) + 2];
                float4 cc3 = u4[(c << 2) + 3];

                // --- off-chain (fills the LDS stall): z is LAGGED (x register
                // still holds x_{t-1} here; readlane of a stale reg = no hazard)
                const float m  = rl(mreg, t0 + q);       // uniform
                float zq = rl(x, 3);
                float z  = (zq > 0.0f) ? zq : 1.0f;      // only t=0 has x[3]==0
                const float s  = ehq[q] * __builtin_amdgcn_rcpf(z);
                const float lg = __log2f(z);             // log2(1)=0 when guarded

                // --- chain: fma tree over this lane's 16 u's ---
                f2 uu[8];
                uu[0].x = cc0.x; uu[0].y = cc0.y;  uu[1].x = cc0.z; uu[1].y = cc0.w;
                uu[2].x = cc1.x; uu[2].y = cc1.y;  uu[3].x = cc1.z; uu[3].y = cc1.w;
                uu[4].x = cc2.x; uu[4].y = cc2.y;  uu[5].x = cc2.z; uu[5].y = cc2.w;
                uu[6].x = cc3.x; uu[6].y = cc3.y;  uu[7].x = cc3.z; uu[7].y = cc3.w;

                float pp[4];
                #pragma unroll
                for (int k = 0; k < 4; ++k) {
                    f2 a    = ew2[k][0] * uu[0];
                    f2 bacc = ew2[k][1] * uu[1];
                    a    = __builtin_elementwise_fma(ew2[k][2], uu[2], a);
                    bacc = __builtin_elementwise_fma(ew2[k][3], uu[3], bacc);
                    a    = __builtin_elementwise_fma(ew2[k][4], uu[4], a);
                    bacc = __builtin_elementwise_fma(ew2[k][5], uu[5], bacc);
                    a    = __builtin_elementwise_fma(ew2[k][6], uu[6], a);
                    bacc = __builtin_elementwise_fma(ew2[k][7], uu[7], bacc);
                    a = a + bacc;
                    pp[k] = a.x + a.y;
                }

                // rotated quad reduce-scatter -> row 4g+c lands in lane 4g+c
                pp[0] += DPPF(pp[1], DPP_X1);
                pp[2] += DPPF(pp[3], DPP_X1);
                pp[0] += DPPF(pp[2], DPP_X2);

                // --- chain tail: one mul, one select ---
                const float xnew = pp[0] * s;
                const bool mm = (m != 0.0f);             // uniform
                x  = mm ? xnew : x;
                Ls = mm ? (Ls + lg) : Ls;
            }
        }
        mreg = mreg_next;
    }

    // out[b] = ln2*Ls + log(sum_i x[i] * exp(trans[EOS, i]))
    float v = x * __expf(trans[EOS_IDX * TAGS + lane]);
    #pragma unroll
    for (int off = 32; off > 0; off >>= 1) v += __shfl_xor(v, off, 64);
    if (lane == 0) out[b] = 0.69314718055994531f * Ls + __logf(v);
}

extern "C" void kernel_launch(void* const* d_in, const int* in_sizes, int n_in,
                              void* d_out, int out_size, void* d_ws, size_t ws_size,
                              hipStream_t stream) {
    const float* h     = (const float*)d_in[0];
    const float* mask  = (const float*)d_in[1];
    const float* trans = (const float*)d_in[2];
    float* out = (float*)d_out;

    const int B = out_size;                 // 512
    const int S = in_sizes[1] / B;          // 1024  (mask is B*S)

    crf_fwd_kernel<<<B, 64, 0, stream>>>(h, mask, trans, out, S);
}

// Round 6
// 328.474 us; speedup vs baseline: 1.0731x; 1.0731x over previous
//
#include <hip/hip_runtime.h>

#define TAGS 64
#define SOS_IDX 1
#define EOS_IDX 2

typedef __attribute__((ext_vector_type(2))) float f2;

// quad_perm DPP: x1 = swap bit0 [1,0,3,2]; x2 = swap bit1 [2,3,0,1]
#define DPP_X1 0xB1
#define DPP_X2 0x4E
#define DPPF(v, ctrl) \
    __int_as_float(__builtin_amdgcn_mov_dpp(__float_as_int(v), (ctrl), 0xF, 0xF, true))

__device__ __forceinline__ float rl(float v, int l) {
    return __int_as_float(__builtin_amdgcn_readlane(__float_as_int(v), l));
}

// One wave per batch; lane i = 4g+c owns tag i.
// x = exp-domain score (score = log x + ln2*Ls). Step:
//   x' = (E x) * s,  s = exp(h_t) * rcp(z),  z = x_prev[3],  Ls += log2(z).
// Chain: cndmask -> ds_write -> 4x ds_read_b128 -> fma tree -> 3x DPP-add -> 1 mul.
// z comes from an extra ds_read_b32 (broadcast, arrives first) so rcp/log2/s all
// execute inside the b128 wait window. No readlane of fresh VGPRs (no SGPR hazards).
__global__ __launch_bounds__(64, 1) void crf_fwd_kernel(
    const float* __restrict__ h,
    const float* __restrict__ mask,
    const float* __restrict__ trans,
    float* __restrict__ out,
    int S)
{
    const int b = blockIdx.x;
    const int lane = threadIdx.x;
    const int g = lane >> 2;
    const int c = lane & 3;

    __shared__ __align__(16) float u_sh[TAGS];

    // E fragment: slot k holds exp(trans[4g + (c^k)][16c .. 16c+16)) as 8 f2.
    f2 ew2[4][8];
    #pragma unroll
    for (int k = 0; k < 4; ++k) {
        const int row = 4 * g + (c ^ k);
        const float4* tr = reinterpret_cast<const float4*>(trans + row * TAGS + 16 * c);
        #pragma unroll
        for (int q = 0; q < 4; ++q) {
            float4 v = tr[q];
            f2 lo, hi;
            lo.x = __expf(v.x); lo.y = __expf(v.y);   // exp(-10000) -> 0 exact
            hi.x = __expf(v.z); hi.y = __expf(v.w);
            ew2[k][2*q]   = lo;
            ew2[k][2*q+1] = hi;
        }
    }

    const float* hb = h + (size_t)b * (size_t)S * TAGS + lane;
    const float* mb = mask + (size_t)b * (size_t)S;

    float x  = (lane == SOS_IDX) ? 1.0f : 0.0f;  // exp(score0)
    float Ls = 0.0f;                              // sum of log2(z)

    // h prefetch, depth 8 (coalesced 256B/wave/step)
    float hbuf[8];
    #pragma unroll
    for (int q = 0; q < 8; ++q) {
        int t = (q < S) ? q : (S - 1);
        hbuf[q] = hb[(size_t)t * TAGS];
    }

    // mask: one coalesced load per 64-step chunk; per-step scalar via readlane of
    // a COLD register (no hazard). S % 64 == 0 (S = 1024).
    const int NC = S >> 6;
    float mreg = mb[lane];

    const float4* u4 = reinterpret_cast<const float4*>(u_sh);

    for (int ch = 0; ch < NC; ++ch) {
        const int cn = (ch + 1 < NC) ? (ch + 1) : ch;
        float mreg_next = mb[(size_t)cn * 64 + lane];   // used 64 steps from now

        for (int t0 = 0; t0 < 64; t0 += 8) {
            float ehq[8];
            #pragma unroll
            for (int q = 0; q < 8; ++q) ehq[q] = __expf(hbuf[q]);
            const int base = ch * 64 + t0 + 8;
            #pragma unroll
            for (int q = 0; q < 8; ++q) {
                int tn = base + q;
                if (tn > S - 1) tn = S - 1;
                hbuf[q] = hb[(size_t)tn * TAGS];
            }

            #pragma unroll
            for (int q = 0; q < 8; ++q) {
                // --- chain head: publish x, z-broadcast first, then 4x b128 ---
                u_sh[lane] = x;
                const float zr = u_sh[3];           // ds_read_b32, broadcast
                float4 cc0 = u4[(c << 2) + 0];
                float4 cc1 = u4[(c << 2) + 1];
                float4 cc2 = u4[(c << 2) + 2];
                float4 cc3 = u4[(c << 2) + 3];
                __builtin_amdgcn_wave_barrier();    // pin store+reads above the rest

                // --- off-chain, runs inside the b128 wait window ---
                const float m = rl(mreg, t0 + q);   // cold reg: no hazard
                const float z = (zr > 0.0f) ? zr : 1.0f;   // only t=0 has x[3]==0
                const float s  = ehq[q] * __builtin_amdgcn_rcpf(z);
                const float lg = __log2f(z);        // feeds Ls only (parallel chain)

                // --- chain: fma tree over this lane's 16 u's ---
                f2 uu[8];
                uu[0].x = cc0.x; uu[0].y = cc0.y;  uu[1].x = cc0.z; uu[1].y = cc0.w;
                uu[2].x = cc1.x; uu[2].y = cc1.y;  uu[3].x = cc1.z; uu[3].y = cc1.w;
                uu[4].x = cc2.x; uu[4].y = cc2.y;  uu[5].x = cc2.z; uu[5].y = cc2.w;
                uu[6].x = cc3.x; uu[6].y = cc3.y;  uu[7].x = cc3.z; uu[7].y = cc3.w;

                float pp[4];
                #pragma unroll
                for (int k = 0; k < 4; ++k) {
                    f2 a    = ew2[k][0] * uu[0];
                    f2 bacc = ew2[k][1] * uu[1];
                    a    = __builtin_elementwise_fma(ew2[k][2], uu[2], a);
                    bacc = __builtin_elementwise_fma(ew2[k][3], uu[3], bacc);
                    a    = __builtin_elementwise_fma(ew2[k][4], uu[4], a);
                    bacc = __builtin_elementwise_fma(ew2[k][5], uu[5], bacc);
                    a    = __builtin_elementwise_fma(ew2[k][6], uu[6], a);
                    bacc = __builtin_elementwise_fma(ew2[k][7], uu[7], bacc);
                    a = a + bacc;
                    pp[k] = a.x + a.y;
                }

                // rotated quad reduce-scatter -> row 4g+c lands in lane 4g+c
                pp[0] += DPPF(pp[1], DPP_X1);
                pp[2] += DPPF(pp[3], DPP_X1);
                pp[0] += DPPF(pp[2], DPP_X2);

                // --- chain tail: one mul, one select ---
                const float xnew = pp[0] * s;
                const bool mm = (m != 0.0f);        // uniform
                x  = mm ? xnew : x;
                Ls = mm ? (Ls + lg) : Ls;
                __builtin_amdgcn_wave_barrier();    // keep R4's proven schedule
            }
        }
        mreg = mreg_next;
    }

    // out[b] = ln2*Ls + log(sum_i x[i] * exp(trans[EOS, i]))
    float v = x * __expf(trans[EOS_IDX * TAGS + lane]);
    #pragma unroll
    for (int off = 32; off > 0; off >>= 1) v += __shfl_xor(v, off, 64);
    if (lane == 0) out[b] = 0.69314718055994531f * Ls + __logf(v);
}

extern "C" void kernel_launch(void* const* d_in, const int* in_sizes, int n_in,
                              void* d_out, int out_size, void* d_ws, size_t ws_size,
                              hipStream_t stream) {
    const float* h     = (const float*)d_in[0];
    const float* mask  = (const float*)d_in[1];
    const float* trans = (const float*)d_in[2];
    float* out = (float*)d_out;

    const int B = out_size;                 // 512
    const int S = in_sizes[1] / B;          // 1024  (mask is B*S)

    crf_fwd_kernel<<<B, 64, 0, stream>>>(h, mask, trans, out, S);
}